// Round 7
// baseline (147.613 us; speedup 1.0000x reference)
//
#include <hip/hip_runtime.h>
#include <hip/hip_bf16.h>
#include <math.h>

#define N_TOK 4096
#define IN_CH 256
#define OUT_CH 64
#define HEADS 8
#define PROJ (OUT_CH * HEADS) /* 512 */
#define NLOG2E -1.44269504088896340736f
#define ZSPLIT 4

typedef float f32x4 __attribute__((ext_vector_type(4)));
typedef __bf16 bf16x8 __attribute__((ext_vector_type(8)));
typedef unsigned short ushort_t;

__device__ inline ushort_t bf16rne(float x) {
    unsigned u = __float_as_uint(x);
    unsigned r = (u + 0x7FFFu + ((u >> 16) & 1u)) >> 16;
    return (ushort_t)r;
}

// ---------------------------------------------------------------------------
// Kernel 0: cast X / Wq / Wk / Wv to bf16 AND pre-permute into MFMA fragment
// order:  flat index (((g*8 + k8)*4 + quad)*16 + t)*8  (g = 16-row group).
// Wq additionally scaled by -log2(e) so sigmoid = rcp(1 + exp2(t)).
// ---------------------------------------------------------------------------
__global__ __launch_bounds__(256) void cast_pack_kernel(
    const float* __restrict__ X,
    const float* __restrict__ Wq, const float* __restrict__ Wk,
    const float* __restrict__ Wv,
    ushort_t* __restrict__ Xa, ushort_t* __restrict__ Wp)
{
    const int i = blockIdx.x * 256 + threadIdx.x;
    const float* src;
    ushort_t* dst;
    float scale = 1.0f;
    if (i < 131072) {                       // X part: N*IN_CH/8 packs
        const int t = i & 15, quad = (i >> 4) & 3, k8 = (i >> 6) & 7, g = i >> 9;
        src = X + (size_t)(g * 16 + t) * IN_CH + k8 * 32 + quad * 8;
        dst = Xa + (size_t)i * 8;
    } else {                                // W part: 3*PROJ*IN_CH/8 packs
        const int j = i - 131072;
        const int z = j >> 14;
        const int r = j & 16383;
        const int cl = r & 15, quad = (r >> 4) & 3, k8 = (r >> 6) & 7, gc = r >> 9;
        const float* W = (z == 0) ? Wq : (z == 1) ? Wk : Wv;
        src = W + (size_t)(gc * 16 + cl) * IN_CH + k8 * 32 + quad * 8;
        dst = Wp + (size_t)z * 131072 * 8 + (size_t)r * 8;
        if (z == 0) scale = NLOG2E;
    }
    float4 a = *(const float4*)src;
    float4 b = *(const float4*)(src + 4);
    ushort_t pk[8];
    pk[0] = bf16rne(a.x * scale); pk[1] = bf16rne(a.y * scale);
    pk[2] = bf16rne(a.z * scale); pk[3] = bf16rne(a.w * scale);
    pk[4] = bf16rne(b.x * scale); pk[5] = bf16rne(b.y * scale);
    pk[6] = bf16rne(b.z * scale); pk[7] = bf16rne(b.w * scale);
    *(uint4*)dst = *(uint4*)pk;
}

// ---------------------------------------------------------------------------
// Kernel 1: Q/K/V projections via bf16 MFMA from frag-packed Xa/Wp.
// grid (PROJ/64, N/64, 3), block 256 (4 waves).  Wave w: 16 tokens x 64 cols.
// Epilogue via LDS transpose; 256 threads store TWO uint4 each (full 8 KB).
//   z=0 -> Qb [N][PROJ] (pre-scaled by -log2e), z=1 -> Kb, z=2 -> Vt [H][64][N]
// ---------------------------------------------------------------------------
__global__ __launch_bounds__(256) void proj_mfma_kernel(
    const ushort_t* __restrict__ Xa, const ushort_t* __restrict__ Wp,
    const float* __restrict__ bq, const float* __restrict__ bk,
    const float* __restrict__ bv,
    ushort_t* __restrict__ Qb, ushort_t* __restrict__ Kb,
    ushort_t* __restrict__ Vt)
{
    const int z = blockIdx.z;
    const float* bias = (z == 0) ? bq : (z == 1) ? bk : bv;
    const float bscale = (z == 0) ? NLOG2E : 1.0f;
    const int c0 = blockIdx.x * 64;
    const int n0 = blockIdx.y * 64;

    const int tid = threadIdx.x;
    const int w = tid >> 6;
    const int lane = tid & 63;
    const int l15 = lane & 15;
    const int quad = lane >> 4;

    __shared__ ushort_t Es[64 * 68];   // epilogue transpose tile (8.7 KB)

    const ushort_t* xa = Xa + (size_t)(blockIdx.y * 4 + w) * 4096 + quad * 128 + l15 * 8;
    const ushort_t* wp0 = Wp + (size_t)z * 131072 * 8 +
                          (size_t)(blockIdx.x * 4) * 4096 + quad * 128 + l15 * 8;

    f32x4 acc[4] = {{0.f, 0.f, 0.f, 0.f}, {0.f, 0.f, 0.f, 0.f},
                    {0.f, 0.f, 0.f, 0.f}, {0.f, 0.f, 0.f, 0.f}};

#pragma unroll 2
    for (int k8 = 0; k8 < 8; ++k8) {
        bf16x8 a = *(const bf16x8*)(xa + k8 * 512);
#pragma unroll
        for (int f = 0; f < 4; ++f) {
            bf16x8 b = *(const bf16x8*)(wp0 + f * 4096 + k8 * 512);
            acc[f] = __builtin_amdgcn_mfma_f32_16x16x32_bf16(a, b, acc[f], 0, 0, 0);
        }
    }

    // bias + bf16 round into LDS (layout depends on z), then coalesced store
    if (z < 2) {
        // Es[tok][c]
#pragma unroll
        for (int f = 0; f < 4; ++f) {
            const float bb = bias[c0 + f * 16 + l15] * bscale;
#pragma unroll
            for (int r = 0; r < 4; ++r)
                Es[(w * 16 + quad * 4 + r) * 68 + f * 16 + l15] = bf16rne(acc[f][r] + bb);
        }
    } else {
        // Es[c][tok]
#pragma unroll
        for (int f = 0; f < 4; ++f) {
            const float bb = bias[c0 + f * 16 + l15];
#pragma unroll
            for (int r = 0; r < 4; ++r)
                Es[(f * 16 + l15) * 68 + w * 16 + quad * 4 + r] = bf16rne(acc[f][r] + bb);
        }
    }
    __syncthreads();

    const int erow = tid >> 2;            // 0..63
    const int ecol = (tid & 3) * 16;      // 0,16,32,48 (+8 second store)
    uint4 pk0 = *(uint4*)&Es[erow * 68 + ecol];
    uint4 pk1 = *(uint4*)&Es[erow * 68 + ecol + 8];
    if (z < 2) {
        ushort_t* out = z ? Kb : Qb;
        ushort_t* p = &out[(size_t)(n0 + erow) * PROJ + c0 + ecol];
        *(uint4*)p = pk0;
        *(uint4*)(p + 8) = pk1;
    } else {
        ushort_t* p = &Vt[(size_t)(c0 + erow) * N_TOK + n0 + ecol];
        *(uint4*)p = pk0;
        *(uint4*)(p + 8) = pk1;
    }
}

// ---------------------------------------------------------------------------
// Kernel 2: fused sigmoid attention with bf16 MFMA (16x16x32).
// grid (N/64, HEADS, ZSPLIT=4) = 2048 blocks -> 6 blocks/CU (LDS-capped;
// launch_bounds(256,6)).  Wave w owns 16 queries; each block does 1024 keys.
// Scores pre-scaled: t = -log2e*(q.k) -> p = rcpf(1 + exp2f(t)).
// P -> bf16 by TRUNCATION (v_perm high bytes).  DEN via MFMA vs ones-frag.
// Partials combined across z-splits via global atomicAdd into zeroed NUM/DEN.
// LDS XOR-swizzled, conflict-free b128 staging + frag reads.
// ---------------------------------------------------------------------------
__global__ __launch_bounds__(256, 6) void attn_kernel(
    const ushort_t* __restrict__ Qb, const ushort_t* __restrict__ Kb,
    const ushort_t* __restrict__ Vt,
    float* __restrict__ NUM, float* __restrict__ DEN)
{
    const int h = blockIdx.y;
    const int z = blockIdx.z;
    const int n0 = blockIdx.x * 64;
    const int tid = threadIdx.x;
    const int w = tid >> 6;
    const int lane = tid & 63;
    const int l15 = lane & 15;
    const int quad = lane >> 4;

    __shared__ ushort_t Ks[64 * 64];      // [l][d] bf16, xor-swizzled chunks
    __shared__ ushort_t Vs[64 * 64];      // [d][l] bf16, xor-swizzled chunks
    __shared__ ushort_t Ps[4][16 * 72];   // per-wave [q][l] bf16 (144B rows)

    // Q B-fragments, register-resident (pre-scaled by -log2e).
    bf16x8 qb[2];
    {
        const ushort_t* base = Qb + (size_t)(n0 + w * 16 + l15) * PROJ + h * 64 + quad * 8;
        qb[0] = *(const bf16x8*)(base);
        qb[1] = *(const bf16x8*)(base + 32);
    }

    bf16x8 onesv;
#pragma unroll
    for (int j = 0; j < 8; ++j) onesv[j] = (__bf16)1.0f;

    f32x4 o[4] = {{0.f, 0.f, 0.f, 0.f}, {0.f, 0.f, 0.f, 0.f},
                  {0.f, 0.f, 0.f, 0.f}, {0.f, 0.f, 0.f, 0.f}};
    f32x4 dacc = {0.f, 0.f, 0.f, 0.f};

    // staging geometry: thread -> (row, 2 consecutive chunks), xor-swizzled
    const int srow = tid >> 2;
    const int sc2 = (tid & 3) * 2;
    const int sp0 = (sc2 ^ (srow & 7)) * 8;
    const int sp1 = ((sc2 + 1) ^ (srow & 7)) * 8;
    // read swizzle: frag row = f*16 + l15 -> mask = l15&7 (per-lane const)
    const int xm = l15 & 7;
    const int rofA = (quad ^ xm) * 8;
    const int rofB = ((4 + quad) ^ xm) * 8;

    const ushort_t* kgp = Kb + (size_t)h * 64 + sc2 * 8 +
                          (size_t)(z * 1024 + srow) * PROJ;
    const ushort_t* vgp = Vt + (size_t)h * 64 * N_TOK + (size_t)srow * N_TOK +
                          sc2 * 8 + z * 1024;

    // prefetch tile 0
    uint4 kr0 = ((const uint4*)kgp)[0], kr1 = ((const uint4*)kgp)[1];
    uint4 vr0 = ((const uint4*)vgp)[0], vr1 = ((const uint4*)vgp)[1];

    for (int lt = 0; lt < 16; ++lt) {
        __syncthreads();              // previous compute done reading LDS
        *(uint4*)&Ks[srow * 64 + sp0] = kr0;
        *(uint4*)&Ks[srow * 64 + sp1] = kr1;
        *(uint4*)&Vs[srow * 64 + sp0] = vr0;
        *(uint4*)&Vs[srow * 64 + sp1] = vr1;
        __syncthreads();              // staging visible

        if (lt < 15) {                // prefetch next tile during compute
            kgp += 64 * PROJ;
            vgp += 64;
            kr0 = ((const uint4*)kgp)[0]; kr1 = ((const uint4*)kgp)[1];
            vr0 = ((const uint4*)vgp)[0]; vr1 = ((const uint4*)vgp)[1];
        }

        // phase 1: T = -log2e * K.Q^T  (D[l][q])
        f32x4 s[4] = {{0.f, 0.f, 0.f, 0.f}, {0.f, 0.f, 0.f, 0.f},
                      {0.f, 0.f, 0.f, 0.f}, {0.f, 0.f, 0.f, 0.f}};
#pragma unroll
        for (int f = 0; f < 4; ++f) {
            bf16x8 ka = *(const bf16x8*)&Ks[(f * 16 + l15) * 64 + rofA];
            s[f] = __builtin_amdgcn_mfma_f32_16x16x32_bf16(ka, qb[0], s[f], 0, 0, 0);
        }
#pragma unroll
        for (int f = 0; f < 4; ++f) {
            bf16x8 ka = *(const bf16x8*)&Ks[(f * 16 + l15) * 64 + rofB];
            s[f] = __builtin_amdgcn_mfma_f32_16x16x32_bf16(ka, qb[1], s[f], 0, 0, 0);
        }

        // sigmoid = rcp(1 + 2^t); truncate to bf16 via perm; pack pairs
        ushort_t* pw = &Ps[w][l15 * 72];
#pragma unroll
        for (int f = 0; f < 4; ++f) {
            float p0 = __builtin_amdgcn_rcpf(1.0f + __builtin_amdgcn_exp2f(s[f][0]));
            float p1 = __builtin_amdgcn_rcpf(1.0f + __builtin_amdgcn_exp2f(s[f][1]));
            float p2 = __builtin_amdgcn_rcpf(1.0f + __builtin_amdgcn_exp2f(s[f][2]));
            float p3 = __builtin_amdgcn_rcpf(1.0f + __builtin_amdgcn_exp2f(s[f][3]));
            uint2 pk;
            pk.x = __builtin_amdgcn_perm(__float_as_uint(p1), __float_as_uint(p0),
                                         0x07060302u);
            pk.y = __builtin_amdgcn_perm(__float_as_uint(p3), __float_as_uint(p2),
                                         0x07060302u);
            *(uint2*)&pw[f * 16 + quad * 4] = pk;
        }

        // phase 2: O += P.V ; DEN += P.1  (A = Ps rows, B = Vs rows / ones)
#pragma unroll
        for (int c = 0; c < 2; ++c) {
            bf16x8 pa = *(const bf16x8*)&Ps[w][l15 * 72 + c * 32 + quad * 8];
            const int rof = c ? rofB : rofA;
#pragma unroll
            for (int f = 0; f < 4; ++f) {
                bf16x8 vb = *(const bf16x8*)&Vs[(f * 16 + l15) * 64 + rof];
                o[f] = __builtin_amdgcn_mfma_f32_16x16x32_bf16(pa, vb, o[f], 0, 0, 0);
            }
            dacc = __builtin_amdgcn_mfma_f32_16x16x32_bf16(pa, onesv, dacc, 0, 0, 0);
        }
    }

    // epilogue: accumulate partial numerator across z-splits (device atomics)
#pragma unroll
    for (int f = 0; f < 4; ++f) {
#pragma unroll
        for (int r = 0; r < 4; ++r) {
            const int q = n0 + w * 16 + quad * 4 + r;
            atomicAdd(&NUM[(size_t)q * PROJ + h * 64 + f * 16 + l15], o[f][r]);
        }
    }
    // DEN: dacc rows are q = quad*4+r, identical across cols; col 0 adds.
    if (l15 == 0) {
#pragma unroll
        for (int r = 0; r < 4; ++r)
            atomicAdd(&DEN[(size_t)(n0 + w * 16 + quad * 4 + r) * HEADS + h], dacc[r]);
    }
}

// ---------------------------------------------------------------------------
// Kernel 3: out[n][d] = (1/8) * sum_h NUM/DEN
// ---------------------------------------------------------------------------
__global__ __launch_bounds__(256) void reduce_kernel(
    const float* __restrict__ NUM, const float* __restrict__ DEN,
    float* __restrict__ out)
{
    const int g = blockIdx.x * 256 + threadIdx.x;
    const int n = g >> 6;
    const int d = g & 63;
    float acc = 0.0f;
#pragma unroll
    for (int hh = 0; hh < HEADS; ++hh)
        acc += NUM[(size_t)n * PROJ + hh * 64 + d] / DEN[(size_t)n * HEADS + hh];
    out[g] = acc * 0.125f;
}

extern "C" void kernel_launch(void* const* d_in, const int* in_sizes, int n_in,
                              void* d_out, int out_size, void* d_ws, size_t ws_size,
                              hipStream_t stream) {
    (void)in_sizes; (void)n_in; (void)out_size; (void)ws_size;
    const float* X  = (const float*)d_in[0];
    const float* Wq = (const float*)d_in[1];
    const float* bq = (const float*)d_in[2];
    const float* Wk = (const float*)d_in[3];
    const float* bk = (const float*)d_in[4];
    const float* Wv = (const float*)d_in[5];
    const float* bv = (const float*)d_in[6];
    float* out = (float*)d_out;

    // ws layout (~22.9 MB total):
    float* NUM = (float*)d_ws;                              // [N][PROJ] f32, 8MB
    float* DEN = NUM + (size_t)N_TOK * PROJ;                // [N][HEADS] f32
    ushort_t* Qb = (ushort_t*)(DEN + (size_t)N_TOK * HEADS);
    ushort_t* Kb = Qb + (size_t)N_TOK * PROJ;
    ushort_t* Vt = Kb + (size_t)N_TOK * PROJ;               // [H][64][N]
    ushort_t* Xa = Vt + (size_t)N_TOK * PROJ;               // frag-packed X
    ushort_t* Wp = Xa + (size_t)N_TOK * IN_CH;              // frag-packed W x3

    // zero the atomic accumulators (NUM+DEN contiguous)
    hipMemsetAsync(NUM, 0, (size_t)(N_TOK * PROJ + N_TOK * HEADS) * 4, stream);
    cast_pack_kernel<<<dim3(704), 256, 0, stream>>>(X, Wq, Wk, Wv, Xa, Wp);
    proj_mfma_kernel<<<dim3(PROJ / 64, N_TOK / 64, 3), 256, 0, stream>>>(
        Xa, Wp, bq, bk, bv, Qb, Kb, Vt);
    attn_kernel<<<dim3(N_TOK / 64, HEADS, ZSPLIT), 256, 0, stream>>>(
        Qb, Kb, Vt, NUM, DEN);
    reduce_kernel<<<dim3(N_TOK * OUT_CH / 256), 256, 0, stream>>>(NUM, DEN, out);
}